// Round 5
// baseline (38.839 us; speedup 1.0000x reference)
//
#include <hip/hip_runtime.h>

#define IN_CH 32
#define OUT_CH 32
#define M1 16
#define M2 16
#define H_ 64
#define W_ 33
#define HW (H_*W_)          // 2112
#define BLPB 8              // batch-l elements per compute block

typedef float f2 __attribute__((ext_vector_type(2)));

// complex MAC: acc += x * w  (x = xr + i*xi, w = wr + i*wi), acc packed (re,im)
__device__ __forceinline__ void cmac(f2& acc, float xr, float xi, float wr, float wi) {
    acc = __builtin_elementwise_fma((f2){xr, xr}, (f2){wr, wi}, acc);
    acc = __builtin_elementwise_fma((f2){-xi, xi}, (f2){wi, wr}, acc);
}

// 1536 blocks x 256 threads.
//   bid%3==0 (512): compute the two mode regions, BLPB bl per block
//   else     (1024): zero-fill the complement (pure write stream)
__global__ __launch_bounds__(256) void spectral_fused(
    const float* __restrict__ x_re, const float* __restrict__ x_im,
    const float* __restrict__ w1_re, const float* __restrict__ w1_im,
    const float* __restrict__ w2_re, const float* __restrict__ w2_im,
    float* __restrict__ out)
{
    const int tid = threadIdx.x;
    const int bid = blockIdx.x;
    const int role = bid % 3;

    if (role) {
        // ---------------- fill role ----------------
        const int fid = (bid / 3) * 2 + (role - 1);   // [0, 1024)
        const int gtid = fid * 256 + tid;
        const int nthreads = 1024 * 256;

        float4* out4 = (float4*)out;
        const float4 z4 = make_float4(0.f, 0.f, 0.f, 0.f);
        const int totalA = 4096 * 528;                // middle band h in [16,48)
        for (int idx = gtid; idx < totalA; idx += nthreads) {
            int plane = idx / 528;
            int k = idx - plane * 528;
            out4[(long)plane * 1056 + 264 + k] = z4;
        }
        float2* out2 = (float2*)out;
        const float2 z2 = make_float2(0.f, 0.f);
        const int totalB = 4096 * 544;                // w-tails of corner bands
        for (int idx = gtid; idx < totalB; idx += nthreads) {
            int plane = idx / 544;
            int r = idx - plane * 544;
            int hh = r / 17;
            int t = r - hh * 17;
            int h = hh < 16 ? hh : hh + 32;
            out2[(long)plane * 2112 + h * 33 + 16 + t] = z2;
        }
        return;
    }

    // ---------------- compute role ----------------
    const int cid = bid / 3;              // [0, 512)
    const int ri = cid >> 4;              // region*16 + i
    const int chunk = cid & 15;           // 16 chunks of BLPB bl
    const int region = ri >> 4;
    const int i = ri & 15;
    const int h = region ? (48 + i) : i;
    const int bl0 = chunk * BLPB;

    __shared__ __align__(16) float2 xs[BLPB][IN_CH][M2];   // 32 KB

    // stage x[bl0.., all c, h, 0..15]; 16 float2 per thread, j-fastest (64B runs)
    for (int item = tid; item < BLPB * IN_CH * M2; item += 256) {
        int j = item & 15;
        int c = (item >> 4) & 31;
        int b = item >> 9;
        long src = (long)((bl0 + b) * IN_CH + c) * HW + (long)h * W_ + j;
        xs[b][c][j] = make_float2(x_re[src], x_im[src]);
    }
    __syncthreads();

    // thread = (bh, o, jq): bh = bl half, o = out channel, jq = j quad
    const int bh = tid >> 7;              // [0,2)
    const int o  = (tid >> 2) & 31;       // [0,32)
    const int jq = tid & 3;               // [0,4)

    const float* wreb = region ? w2_re : w1_re;
    const float* wimb = region ? w2_im : w1_im;
    // float4 index: (c*8192 + o*256 + i*16 + jq*4) / 4
    const float4* __restrict__ wre4 = (const float4*)wreb + (o * 64 + i * 4 + jq);
    const float4* __restrict__ wim4 = (const float4*)wimb + (o * 64 + i * 4 + jq);

    f2 acc[4][4];
    #pragma unroll
    for (int bb = 0; bb < 4; ++bb)
        #pragma unroll
        for (int jj = 0; jj < 4; ++jj)
            acc[bb][jj] = (f2){0.f, 0.f};

    // software-pipelined c-loop: 2 float4 weight loads feed 128 FMAs
    float4 wr = wre4[0], wi = wim4[0];
    #pragma unroll 4
    for (int c = 0; c < IN_CH; ++c) {
        float4 wrn, win;
        if (c < IN_CH - 1) {
            wrn = wre4[(c + 1) * 2048];
            win = wim4[(c + 1) * 2048];
        }
        #pragma unroll
        for (int bb = 0; bb < 4; ++bb) {
            const float4* xp = (const float4*)&xs[bh * 4 + bb][c][jq * 4];
            float4 x01 = xp[0];           // complex j0, j1
            float4 x23 = xp[1];           // complex j2, j3
            cmac(acc[bb][0], x01.x, x01.y, wr.x, wi.x);
            cmac(acc[bb][1], x01.z, x01.w, wr.y, wi.y);
            cmac(acc[bb][2], x23.x, x23.y, wr.z, wi.z);
            cmac(acc[bb][3], x23.z, x23.w, wr.w, wi.w);
        }
        wr = wrn; wi = win;
    }

    float2* out2 = (float2*)out;
    #pragma unroll
    for (int bb = 0; bb < 4; ++bb) {
        int bl = bl0 + bh * 4 + bb;
        long rowbase = ((long)(bl * OUT_CH + o) * H_ + h) * W_ + jq * 4;  // float2 units
        #pragma unroll
        for (int jj = 0; jj < 4; ++jj)
            out2[rowbase + jj] = make_float2(acc[bb][jj].x, acc[bb][jj].y);
    }
}

extern "C" void kernel_launch(void* const* d_in, const int* in_sizes, int n_in,
                              void* d_out, int out_size, void* d_ws, size_t ws_size,
                              hipStream_t stream) {
    const float* x_re  = (const float*)d_in[0];
    const float* x_im  = (const float*)d_in[1];
    const float* w1_re = (const float*)d_in[2];
    const float* w1_im = (const float*)d_in[3];
    const float* w2_re = (const float*)d_in[4];
    const float* w2_im = (const float*)d_in[5];
    float* out = (float*)d_out;

    spectral_fused<<<dim3(1536), dim3(256), 0, stream>>>(
        x_re, x_im, w1_re, w1_im, w2_re, w2_im, out);
}